// Round 1
// baseline (394.623 us; speedup 1.0000x reference)
//
#include <hip/hip_runtime.h>

// Problem constants (from reference): E=8, N=8192, D=1024, LOAD=16384
#define D_CONST    1024
#define CAP        64          // bucket capacity; mean occupancy is 4 (Poisson), 64 is ~impossible to hit

// Kernel 1: one thread per input row; count tags and record row index in bucket.
__global__ void gr_build_index(const int* __restrict__ tags,
                               int* __restrict__ counts,
                               int* __restrict__ idx,
                               int* __restrict__ pos_arr,
                               int total) {
    int i = blockIdx.x * blockDim.x + threadIdx.x;
    if (i >= total) return;
    int t = tags[i];
    int pos = atomicAdd(&counts[t], 1);   // device-scope by default (cross-XCD safe)
    pos_arr[i] = pos;
    if (pos < CAP) idx[t * CAP + pos] = i;
}

// Kernel 2: one block per output row. 256 threads x float4 = 1024 floats = D.
// Gather-sum all contributing input rows; deterministic, no float atomics.
__global__ void __launch_bounds__(256)
gr_gather_sum(const float* __restrict__ data,
              const int* __restrict__ counts,
              const int* __restrict__ idx,
              float* __restrict__ out) {
    const int r   = blockIdx.x;
    const int tid = threadIdx.x;
    int cnt = counts[r];
    if (cnt > CAP) cnt = CAP;
    const int* __restrict__ rowlist = idx + r * CAP;
    const int col = tid * 4;

    float4 acc = make_float4(0.f, 0.f, 0.f, 0.f);
    for (int j = 0; j < cnt; ++j) {
        int row = rowlist[j];                         // block-uniform -> scalar load
        const float4 v = *reinterpret_cast<const float4*>(
            data + (size_t)row * D_CONST + col);      // coalesced 4KB row read
        acc.x += v.x; acc.y += v.y; acc.z += v.z; acc.w += v.w;
    }
    *reinterpret_cast<float4*>(out + (size_t)r * D_CONST + col) = acc;  // slots with cnt==0 get zeros
}

// Kernel 3: overflow fixup (bucket fuller than CAP) — statistically never runs.
__global__ void gr_overflow(const float* __restrict__ data,
                            const int* __restrict__ tags,
                            const int* __restrict__ pos_arr,
                            float* __restrict__ out,
                            int total) {
    int i = blockIdx.x * blockDim.x + threadIdx.x;
    if (i >= total) return;
    if (pos_arr[i] < CAP) return;   // uniform-ish skip; near-zero cost
    int t = tags[i];
    const float* src = data + (size_t)i * D_CONST;
    float* dst = out + (size_t)t * D_CONST;
    for (int c = 0; c < D_CONST; ++c) atomicAdd(&dst[c], src[c]);
}

// Fallback: direct atomic scatter if workspace is too small (needs zeroed out).
__global__ void __launch_bounds__(256)
gr_atomic_scatter(const float* __restrict__ data,
                  const int* __restrict__ tags,
                  float* __restrict__ out,
                  int total) {
    const int row = blockIdx.x;
    if (row >= total) return;
    const int t = tags[row];
    const int col = threadIdx.x * 4;
    const float4 v = *reinterpret_cast<const float4*>(
        data + (size_t)row * D_CONST + col);
    float* dst = out + (size_t)t * D_CONST + col;
    atomicAdd(&dst[0], v.x);
    atomicAdd(&dst[1], v.y);
    atomicAdd(&dst[2], v.z);
    atomicAdd(&dst[3], v.w);
}

extern "C" void kernel_launch(void* const* d_in, const int* in_sizes, int n_in,
                              void* d_out, int out_size, void* d_ws, size_t ws_size,
                              hipStream_t stream) {
    const float* data = (const float*)d_in[0];   // (E,N,D) fp32
    const int*   tags = (const int*)d_in[1];     // (E,N) as int32
    // d_in[2] is the scalar `load`; fixed at 16384 for this problem.

    const int total = in_sizes[1];               // E*N = 65536
    const int load  = out_size / D_CONST;        // 16384

    float* out = (float*)d_out;

    // Workspace layout: [counts: load ints][pos: total ints][idx: load*CAP ints]
    const size_t counts_bytes = (size_t)load * sizeof(int);
    const size_t pos_bytes    = (size_t)total * sizeof(int);
    const size_t idx_bytes    = (size_t)load * CAP * sizeof(int);
    const size_t needed       = counts_bytes + pos_bytes + idx_bytes;

    if (ws_size >= needed) {
        int* counts = (int*)d_ws;
        int* pos    = (int*)((char*)d_ws + counts_bytes);
        int* idx    = (int*)((char*)d_ws + counts_bytes + pos_bytes);

        hipMemsetAsync(counts, 0, counts_bytes, stream);

        gr_build_index<<<(total + 255) / 256, 256, 0, stream>>>(tags, counts, idx, pos, total);
        gr_gather_sum<<<load, 256, 0, stream>>>(data, counts, idx, out);
        gr_overflow<<<(total + 255) / 256, 256, 0, stream>>>(data, tags, pos, out, total);
    } else {
        // Fallback: zero output, then atomic scatter (non-deterministic order, fp32 ok).
        hipMemsetAsync(out, 0, (size_t)out_size * sizeof(float), stream);
        gr_atomic_scatter<<<total, 256, 0, stream>>>(data, tags, out, total);
    }
}

// Round 2
// 391.809 us; speedup vs baseline: 1.0072x; 1.0072x over previous
//
#include <hip/hip_runtime.h>

// Problem constants (from reference): E=8, N=8192, D=1024, LOAD=16384
#define D_CONST    1024
#define CAP        64   // bucket capacity; mean occupancy 4 (Poisson) -> overflow ~impossible,
                        // but gather has a correct full-scan fallback if it happens.

// Kernel 1: one thread per input row; count tags and record row index in bucket.
__global__ void gr_build_index(const int* __restrict__ tags,
                               int* __restrict__ counts,
                               int* __restrict__ idx,
                               int total) {
    int i = blockIdx.x * blockDim.x + threadIdx.x;
    if (i >= total) return;
    int t = tags[i];
    int pos = atomicAdd(&counts[t], 1);   // device-scope by default
    if (pos < CAP) idx[t * CAP + pos] = i;
}

// Kernel 2: one block per output row. 256 threads x float4 = 1024 floats = D.
// Row indices prefetched 4-at-a-time (uniform int4 load) so the 4 row reads
// (1 KB/wave each) are independent and in flight together.
__global__ void __launch_bounds__(256)
gr_gather_sum(const float* __restrict__ data,
              const int* __restrict__ counts,
              const int* __restrict__ idx,
              const int* __restrict__ tags,
              float* __restrict__ out,
              int total) {
    const int r   = blockIdx.x;
    const int col = threadIdx.x * 4;
    const int cnt = counts[r];

    float4 acc = make_float4(0.f, 0.f, 0.f, 0.f);

    if (cnt <= CAP) {
        const int* __restrict__ rowlist = idx + r * CAP;
        int j = 0;
        for (; j + 4 <= cnt; j += 4) {
            const int4 rw = *reinterpret_cast<const int4*>(rowlist + j);  // uniform 16B
            const float4 v0 = *reinterpret_cast<const float4*>(data + (size_t)rw.x * D_CONST + col);
            const float4 v1 = *reinterpret_cast<const float4*>(data + (size_t)rw.y * D_CONST + col);
            const float4 v2 = *reinterpret_cast<const float4*>(data + (size_t)rw.z * D_CONST + col);
            const float4 v3 = *reinterpret_cast<const float4*>(data + (size_t)rw.w * D_CONST + col);
            acc.x += (v0.x + v1.x) + (v2.x + v3.x);
            acc.y += (v0.y + v1.y) + (v2.y + v3.y);
            acc.z += (v0.z + v1.z) + (v2.z + v3.z);
            acc.w += (v0.w + v1.w) + (v2.w + v3.w);
        }
        for (; j < cnt; ++j) {
            const int row = rowlist[j];
            const float4 v = *reinterpret_cast<const float4*>(data + (size_t)row * D_CONST + col);
            acc.x += v.x; acc.y += v.y; acc.z += v.z; acc.w += v.w;
        }
    } else {
        // Overflow fallback (statistically never taken): scan all tags, sum matches.
        for (int i = 0; i < total; ++i) {
            if (tags[i] == r) {
                const float4 v = *reinterpret_cast<const float4*>(data + (size_t)i * D_CONST + col);
                acc.x += v.x; acc.y += v.y; acc.z += v.z; acc.w += v.w;
            }
        }
    }

    *reinterpret_cast<float4*>(out + (size_t)r * D_CONST + col) = acc;  // cnt==0 -> zeros
}

// Fallback: direct atomic scatter if workspace is too small (needs zeroed out).
__global__ void __launch_bounds__(256)
gr_atomic_scatter(const float* __restrict__ data,
                  const int* __restrict__ tags,
                  float* __restrict__ out,
                  int total) {
    const int row = blockIdx.x;
    if (row >= total) return;
    const int t = tags[row];
    const int col = threadIdx.x * 4;
    const float4 v = *reinterpret_cast<const float4*>(data + (size_t)row * D_CONST + col);
    float* dst = out + (size_t)t * D_CONST + col;
    atomicAdd(&dst[0], v.x);
    atomicAdd(&dst[1], v.y);
    atomicAdd(&dst[2], v.z);
    atomicAdd(&dst[3], v.w);
}

extern "C" void kernel_launch(void* const* d_in, const int* in_sizes, int n_in,
                              void* d_out, int out_size, void* d_ws, size_t ws_size,
                              hipStream_t stream) {
    const float* data = (const float*)d_in[0];   // (E,N,D) fp32
    const int*   tags = (const int*)d_in[1];     // (E,N) int32
    const int total = in_sizes[1];               // E*N = 65536
    const int load  = out_size / D_CONST;        // 16384
    float* out = (float*)d_out;

    // Workspace layout: [counts: load ints][idx: load*CAP ints]
    const size_t counts_bytes = (size_t)load * sizeof(int);
    const size_t idx_bytes    = (size_t)load * CAP * sizeof(int);
    const size_t needed       = counts_bytes + idx_bytes;

    if (ws_size >= needed) {
        int* counts = (int*)d_ws;
        int* idx    = (int*)((char*)d_ws + counts_bytes);

        hipMemsetAsync(counts, 0, counts_bytes, stream);
        gr_build_index<<<(total + 255) / 256, 256, 0, stream>>>(tags, counts, idx, total);
        gr_gather_sum<<<load, 256, 0, stream>>>(data, counts, idx, tags, out, total);
    } else {
        hipMemsetAsync(out, 0, (size_t)out_size * sizeof(float), stream);
        gr_atomic_scatter<<<total, 256, 0, stream>>>(data, tags, out, total);
    }
}